// Round 11
// baseline (264.800 us; speedup 1.0000x reference)
//
#include <hip/hip_runtime.h>
#include <math.h>

// ---------------------------------------------------------------------------
// R11: R10 structure with TWO blocks per CU (correct version of R9's intent).
// 512 threads (8 waves), MT=64 rows/block, grid = 16384/64 = 256 blocks ->
// 2 blocks resident per CU (LDS 71 KB <= 80 KB). Lane = batch row over
// exactly 64 rows per wave (required for wave-uniform s_load weights — R9's
// crash was grid=512 overrunning the batch, not the concept). NJ=16 for the
// 128-wide layers -> 64 FMA per ds_read_b128. The two blocks form
// independent barrier domains: while one drains __syncthreads / waits on the
// scalar weight stream, the other issues — attacking the 54% stall R8/R10
// measured at 1 block/CU. NO min-waves launch bound (R4: spills).
// Quad-packed activations: buf[(c>>2)*256 + r*4 + (c&3)] -> conflict-free.
// ---------------------------------------------------------------------------

__device__ __forceinline__ void encode_card32(int c,
                                              const float* __restrict__ val_emb,
                                              const float* __restrict__ suit_emb,
                                              const float* __restrict__ type_emb,
                                              float* e) {
  bool inv = (c == 0) || (c == 53);
  int v = inv ? 0 : ((c - 1) % 13 + 1);
  int s = inv ? 0 : ((c - 1) / 13 + 1);
  int ct = (v == 11) ? 1 : (v == 12) ? 2 : (v == 13) ? 3 : 0;
#pragma unroll
  for (int i = 0; i < 16; ++i) e[i] = val_emb[v * 16 + i];
#pragma unroll
  for (int i = 0; i < 16; ++i) e[16 + i] = suit_emb[s * 16 + i];
#pragma unroll
  for (int i = 0; i < 8; ++i) e[i] += type_emb[ct * 8 + i];
}

// ---------------------------------------------------------------------------
// Kernel 1: per-action precompute (A=30), 1 block x 64 threads. Writes ws:
//   ws[0..1919] Qa[a][j];  ws[1920..1949] strength;  ws[1950..1979] has_valid
// ---------------------------------------------------------------------------
__global__ __launch_bounds__(64) void action_kernel(
    const int* __restrict__ acards,
    const float* __restrict__ val_emb, const float* __restrict__ suit_emb,
    const float* __restrict__ type_emb,
    const float* __restrict__ ce_w1, const float* __restrict__ ce_b1,
    const float* __restrict__ ce_w2, const float* __restrict__ ce_b2,
    const float* __restrict__ as_w1, const float* __restrict__ as_b1,
    float* __restrict__ ws) {
  __shared__ float sAct[30][32];
  __shared__ float sCombo[30][16];
  const int tid = threadIdx.x;

  if (tid < 30) {
    int c[4];
#pragma unroll
    for (int i = 0; i < 4; ++i) c[i] = acards[tid * 4 + i];
    bool mask[4]; int vals[4], suits[4]; int csize = 0; bool hasv = false;
#pragma unroll
    for (int i = 0; i < 4; ++i) {
      mask[i] = (c[i] != 0);
      if (mask[i]) { csize++; hasv = true; }
      vals[i] = mask[i] ? ((c[i] - 1) % 13 + 1) : 0;
      suits[i] = mask[i] ? ((c[i] - 1) / 13 + 1) : 0;
    }
    int fvv = mask[0] ? vals[0] : mask[1] ? vals[1] : mask[2] ? vals[2]
              : mask[3] ? vals[3] : vals[0];
    bool same = true;
#pragma unroll
    for (int i = 0; i < 4; ++i) if (mask[i] && vals[i] != fvv) same = false;
    float total = 0.f;
#pragma unroll
    for (int i = 0; i < 4; ++i) {
      if (mask[i]) {
        int v = vals[i];
        total += (v == 1) ? 1.f : (v == 11) ? 10.f : (v == 12) ? 15.f
                 : (v == 13) ? 20.f : (float)v;
      }
    }
    float uniq = 0.f;
#pragma unroll
    for (int s = 1; s <= 4; ++s) {
      bool any = false;
#pragma unroll
      for (int i = 0; i < 4; ++i) if (suits[i] == s) any = true;
      uniq += any ? 1.f : 0.f;
    }
    bool ace = false;
#pragma unroll
    for (int i = 0; i < 4; ++i) if (mask[i] && vals[i] == 1) ace = true;
    float f_same = same ? 1.f : 0.f, f_ace = ace ? 1.f : 0.f;
    float valid = (((float)csize <= 4.f) && (f_same > 0.f || f_ace > 0.f)) ? 1.f : 0.f;
    float feats[6] = {(float)csize, f_same, total, uniq, f_ace, valid};
    if (!hasv) { for (int i = 0; i < 6; ++i) feats[i] = 0.f; }
    float emb[32];
#pragma unroll
    for (int i = 0; i < 32; ++i) emb[i] = 0.f;
    float cnt = 0.f;
#pragma unroll
    for (int i = 0; i < 4; ++i) {
      float e[32];
      encode_card32(c[i], val_emb, suit_emb, type_emb, e);
      if (mask[i]) {
#pragma unroll
        for (int j = 0; j < 32; ++j) emb[j] += e[j];
        cnt += 1.f;
      }
    }
    float invc = 1.f / fmaxf(cnt, 1.f);
#pragma unroll
    for (int j = 0; j < 32; ++j) sAct[tid][j] = hasv ? emb[j] * invc : 0.f;
    float t32[32];
#pragma unroll
    for (int j = 0; j < 32; ++j) {
      float acc = ce_b1[j];
#pragma unroll
      for (int k = 0; k < 6; ++k) acc += feats[k] * ce_w1[k * 32 + j];
      t32[j] = fmaxf(acc, 0.f);
    }
#pragma unroll
    for (int j = 0; j < 16; ++j) {
      float acc = ce_b2[j];
#pragma unroll
      for (int k = 0; k < 32; ++k) acc += t32[k] * ce_w2[k * 16 + j];
      sCombo[tid][j] = acc;
    }
    ws[1920 + tid] = total * 0.05f;
    ws[1950 + tid] = hasv ? 1.f : 0.f;
  }
  __syncthreads();
  for (int idx = tid; idx < 1920; idx += 64) {
    int a = idx >> 6, j = idx & 63;
    float acc = as_b1[j];
#pragma unroll
    for (int k = 0; k < 32; ++k) acc += sAct[a][k] * as_w1[(128 + k) * 64 + j];
#pragma unroll
    for (int k = 0; k < 16; ++k) acc += sCombo[a][k] * as_w1[(160 + k) * 64 + j];
    ws[idx] = acc;
  }
}

// ---------------------------------------------------------------------------
// Unified layer: QIN = quad-packed input (ds_read_b128, 4 k per read),
// else simple [k][64]. QOUT = quad-packed output. W read wave-uniformly
// (s_load + SGPR-operand FMA).
// ---------------------------------------------------------------------------
template <int K, int NJ, bool RELU, bool HASB, bool QIN, bool QOUT>
__device__ __forceinline__ void layerU(
    const float* __restrict__ in, int inColBase, float* __restrict__ outB,
    int outColBase, const float* __restrict__ W, int ldw, int j0,
    const float* __restrict__ bias, int r) {
  float acc[NJ];
#pragma unroll
  for (int j = 0; j < NJ; ++j) acc[j] = HASB ? bias[j0 + j] : 0.f;
  if constexpr (QIN) {
    static_assert(K % 4 == 0, "quad input needs K%4==0");
    const int g0 = inColBase >> 2;
#pragma unroll 4
    for (int g = 0; g < K / 4; ++g) {
      float4 a = *(const float4*)&in[(g0 + g) * 256 + r * 4];
#pragma unroll
      for (int q = 0; q < 4; ++q) {
        float av = (q == 0) ? a.x : (q == 1) ? a.y : (q == 2) ? a.z : a.w;
        const float* wr = W + (size_t)(g * 4 + q) * ldw + j0;
#pragma unroll
        for (int j = 0; j < NJ; ++j) acc[j] += av * wr[j];
      }
    }
  } else {
#pragma unroll 4
    for (int k = 0; k < K; ++k) {
      float a = in[(inColBase + k) * 64 + r];
      const float* wr = W + (size_t)k * ldw + j0;
#pragma unroll
      for (int j = 0; j < NJ; ++j) acc[j] += a * wr[j];
    }
  }
#pragma unroll
  for (int j = 0; j < NJ; ++j) if (RELU) acc[j] = fmaxf(acc[j], 0.f);
  if constexpr (QOUT && (NJ % 4 == 0)) {
    const int c0 = outColBase + j0;      // quad-aligned by construction
#pragma unroll
    for (int qg = 0; qg < NJ / 4; ++qg) {
      float4 o = make_float4(acc[qg * 4], acc[qg * 4 + 1],
                             acc[qg * 4 + 2], acc[qg * 4 + 3]);
      *(float4*)&outB[((c0 >> 2) + qg) * 256 + r * 4] = o;
    }
  } else {
#pragma unroll
    for (int j = 0; j < NJ; ++j) outB[(outColBase + j0 + j) * 64 + r] = acc[j];
  }
}

// ---------------------------------------------------------------------------
// Main kernel. 64 rows/block, 512 threads (8 waves), grid 256 (2 blocks/CU).
// bufA (quad, 152 cols): combined [0:32) hand_ctx | [32:64) enemy |
//   [64:96) strat_ctx | [96:150) discard  -> later h2 (128) ->
//   later t1 cols [0:64) | P cols [64:128)
// bufB: simple rows [0:20) strat_in | [20:84) t64 | [84:116) V | 116 sLen
//   -> later quad h1 (128) -> quad ctx (128) -> logits rows [0:4)
// ---------------------------------------------------------------------------
__global__ __launch_bounds__(512) void policy_main(
    const int* __restrict__ hand_cards, const int* __restrict__ enemy_card,
    const int* __restrict__ hand_size, const float* __restrict__ game_state,
    const float* __restrict__ discard,
    const float* __restrict__ val_emb, const float* __restrict__ suit_emb,
    const float* __restrict__ type_emb,
    const float* __restrict__ he_wv, const float* __restrict__ he_bv,
    const float* __restrict__ he_wo, const float* __restrict__ he_bo,
    const float* __restrict__ se_w1, const float* __restrict__ se_b1,
    const float* __restrict__ se_w2, const float* __restrict__ se_b2,
    const float* __restrict__ atc_w1, const float* __restrict__ atc_b1,
    const float* __restrict__ atc_w2, const float* __restrict__ atc_b2,
    const float* __restrict__ as_w1,
    const float* __restrict__ as_w2, const float* __restrict__ as_b2,
    const float* __restrict__ as_w3, const float* __restrict__ as_b3,
    const float* __restrict__ cx_w1, const float* __restrict__ cx_b1,
    const float* __restrict__ cx_w2, const float* __restrict__ cx_b2,
    const float* __restrict__ cx_w3, const float* __restrict__ cx_b3,
    const float* __restrict__ ws, float* __restrict__ out) {
  __shared__ float bufA[38 * 256];   // 38 quad groups = 152 cols, 38 KB
  __shared__ float bufB[128 * 64];   // 32 KB   (total ~71 KB -> 2 blocks/CU)

  const int tid = threadIdx.x;
  const int r = tid & 63;                                   // lane = batch row
  const int wq = __builtin_amdgcn_readfirstlane(tid >> 6);  // wave id 0..7
  const int b0 = blockIdx.x * 64;                           // grid 256 = 16384/64

  // ---------------- P0: staging + per-row features --------------------------
  // discard -> bufA quad cols [96:150)  (all threads)
  for (int idx = tid; idx < 64 * 54; idx += 512) {
    int rr = idx / 54, k = idx - rr * 54;
    int c = 96 + k;
    bufA[(c >> 2) * 256 + rr * 4 + (c & 3)] = discard[(size_t)b0 * 54 + idx];
  }
  if (wq == 2) {                                            // game_state rows 0..9
#pragma unroll
    for (int k = 0; k < 10; ++k)
      bufB[k * 64 + r] = game_state[(size_t)(b0 + r) * 10 + k];
  }
  if (wq == 0) {                                            // hand features rows 10..19
    const int b = b0 + r;
    const float hsz = (float)hand_size[b];
    int aces = 0, faces = 0, low = 0, c1 = 0, c2 = 0, c3 = 0, c4 = 0;
#pragma unroll
    for (int i = 0; i < 8; ++i) {
      int c = hand_cards[b * 8 + i];
      int v = (c == 0) ? 0 : ((c - 1) % 13 + 1);
      int s = (c == 0) ? 0 : ((c - 1) / 13 + 1);
      aces += (v == 1);
      faces += (v >= 11 && v <= 13);
      low += (v >= 2 && v <= 6);
      c1 += (s == 1); c2 += (s == 2); c3 += (s == 3); c4 += (s == 4);
    }
    float sdiv = (float)((c1 > 0) + (c2 > 0) + (c3 > 0) + (c4 > 0)) * 0.25f;
    float hvr = (float)faces / (hsz + 1e-8f);
    bufB[(10 + 0) * 64 + r] = hsz;          bufB[(10 + 1) * 64 + r] = (float)aces;
    bufB[(10 + 2) * 64 + r] = (float)faces; bufB[(10 + 3) * 64 + r] = (float)low;
    bufB[(10 + 4) * 64 + r] = (float)c1;    bufB[(10 + 5) * 64 + r] = (float)c2;
    bufB[(10 + 6) * 64 + r] = (float)c3;    bufB[(10 + 7) * 64 + r] = (float)c4;
    bufB[(10 + 8) * 64 + r] = hvr;          bufB[(10 + 9) * 64 + r] = sdiv;
  }
  if (wq == 1) {                                            // enemy (quad) + sLen
    const int b = b0 + r;
    bufB[116 * 64 + r] = 8.0f / fmaxf((float)hand_size[b], 1.0f);
    float e[32];
    encode_card32(enemy_card[b], val_emb, suit_emb, type_emb, e);
#pragma unroll
    for (int g = 0; g < 8; ++g) {
      float4 ev = make_float4(e[g * 4], e[g * 4 + 1], e[g * 4 + 2], e[g * 4 + 3]);
      *(float4*)&bufA[(8 + g) * 256 + r * 4] = ev;   // cols 32..63
    }
  }
  __syncthreads();

  // ---------------- Phase A (task-parallel): se L1 | V -----------------------
  if (wq < 4) {
    // se L1 20->64 relu: bufB rows[0:20) -> rows [20:84), 4 waves x NJ=16
    layerU<20, 16, true, true, false, false>(bufB, 0, bufB, 20, se_w1, 64,
                                             wq * 16, se_b1, r);
  } else {
    // V = enemy@he_wv + bv: bufA quad cols[32:64) -> bufB rows [84:116), NJ=8
    layerU<32, 8, false, true, true, false>(bufA, 32, bufB, 84, he_wv, 32,
                                            (wq - 4) * 8, he_bv, r);
  }
  __syncthreads();

  // ---------------- Phase B (task-parallel): se L2 | hand_ctx ----------------
  if (wq < 4) {
    // strat_ctx = t64@se_w2 + b: bufB rows[20:84) -> bufA quad cols [64:96)
    layerU<64, 8, false, true, false, true>(bufB, 20, bufA, 64, se_w2, 32,
                                            wq * 8, se_b2, r);
  } else {
    // hand_ctx = (V@he_wo + bo) * 8/len -> bufA quad cols [0:32), NJ=8
    const int j0 = (wq - 4) * 8;
    float acc[8];
#pragma unroll
    for (int j = 0; j < 8; ++j) acc[j] = he_bo[j0 + j];
#pragma unroll 4
    for (int k = 0; k < 32; ++k) {
      float a = bufB[(84 + k) * 64 + r];
      const float* wr = he_wo + (size_t)k * 32 + j0;
#pragma unroll
      for (int j = 0; j < 8; ++j) acc[j] += a * wr[j];
    }
    float scale = bufB[116 * 64 + r];
#pragma unroll
    for (int qg = 0; qg < 2; ++qg) {
      float4 o = make_float4(scale * acc[qg * 4], scale * acc[qg * 4 + 1],
                             scale * acc[qg * 4 + 2], scale * acc[qg * 4 + 3]);
      *(float4*)&bufA[((j0 >> 2) + qg) * 256 + r * 4] = o;
    }
  }
  __syncthreads();

  // ---------------- L1: 150->128 relu, all input in LDS (37 quads + tail) ----
  {
    const int j0 = wq * 16;
    float acc[16];
#pragma unroll
    for (int j = 0; j < 16; ++j) acc[j] = cx_b1[j0 + j];
#pragma unroll 4
    for (int g = 0; g < 37; ++g) {
      float4 a = *(const float4*)&bufA[g * 256 + r * 4];
#pragma unroll
      for (int q = 0; q < 4; ++q) {
        float av = (q == 0) ? a.x : (q == 1) ? a.y : (q == 2) ? a.z : a.w;
        const float* wr = cx_w1 + (size_t)(g * 4 + q) * 128 + j0;
#pragma unroll
        for (int j = 0; j < 16; ++j) acc[j] += av * wr[j];
      }
    }
    {  // tail: cols 148,149 (discard elements 52,53)
      float4 a = *(const float4*)&bufA[37 * 256 + r * 4];
      const float* wr0 = cx_w1 + (size_t)148 * 128 + j0;
      const float* wr1 = cx_w1 + (size_t)149 * 128 + j0;
#pragma unroll
      for (int j = 0; j < 16; ++j) acc[j] += a.x * wr0[j] + a.y * wr1[j];
    }
#pragma unroll
    for (int qg = 0; qg < 4; ++qg) {
      float4 o = make_float4(fmaxf(acc[qg * 4], 0.f), fmaxf(acc[qg * 4 + 1], 0.f),
                             fmaxf(acc[qg * 4 + 2], 0.f), fmaxf(acc[qg * 4 + 3], 0.f));
      *(float4*)&bufB[((j0 >> 2) + qg) * 256 + r * 4] = o;   // h1 quad
    }
  }
  __syncthreads();

  // ---------------- L2: 128->128 relu  (bufB quad -> bufA quad) -------------
  layerU<128, 16, true, true, true, true>(bufB, 0, bufA, 0, cx_w2, 128, wq * 16,
                                          cx_b2, r);
  __syncthreads();

  // ---------------- L3: 128->128 (ctx)  (bufA quad -> bufB quad) ------------
  layerU<128, 16, false, true, true, true>(bufA, 0, bufB, 0, cx_w3, 128, wq * 16,
                                           cx_b3, r);
  __syncthreads();

  // ---------------- P7: t1 (waves 0-3) | P (waves 4-7)  (bufB -> bufA) ------
  if (wq < 4) {
    layerU<128, 16, true, true, true, true>(bufB, 0, bufA, 0, atc_w1, 64,
                                            wq * 16, atc_b1, r);
  } else {
    layerU<128, 16, false, false, true, true>(bufB, 0, bufA, 64, as_w1, 64,
                                              (wq - 4) * 16, nullptr, r);
  }
  __syncthreads();

  // ---------------- P8: 4 type logits (wave wq<4 computes logit wq) ---------
  if (wq < 4) {
    float acc = atc_b2[wq];
#pragma unroll 4
    for (int g = 0; g < 16; ++g) {                 // t1 = bufA quad groups 0..15
      float4 t = *(const float4*)&bufA[g * 256 + r * 4];
      acc += t.x * atc_w2[(g * 4 + 0) * 4 + wq];
      acc += t.y * atc_w2[(g * 4 + 1) * 4 + wq];
      acc += t.z * atc_w2[(g * 4 + 2) * 4 + wq];
      acc += t.w * atc_w2[(g * 4 + 3) * 4 + wq];
    }
    bufB[wq * 64 + r] = acc;   // overwrites dead ctx quad group 0
  }
  __syncthreads();

  // ---------------- P9: scoring. waves 0-6 -> 4 actions, wave 7 -> 2 --------
  {
    float l0 = bufB[0 * 64 + r], l1 = bufB[1 * 64 + r];
    float l2 = bufB[2 * 64 + r], l3 = bufB[3 * 64 + r];
    float m = fmaxf(fmaxf(l0, l1), fmaxf(l2, l3));
    float e0 = expf(l0 - m), e1 = expf(l1 - m), e2 = expf(l2 - m), e3 = expf(l3 - m);
    float inv = 1.f / (e0 + e1 + e2 + e3);
    float tp0 = e0 * inv, tp1 = e1 * inv, tp3 = e3 * inv;

    const int acnt = (wq < 7) ? 4 : 2;
    const float b3v = as_b3[0];
#pragma unroll 1
    for (int i = 0; i < acnt; ++i) {
      const int a = wq * 4 + i;                // wave-uniform
      const float* qa = ws + a * 64;           // uniform -> s_load
      float acc[32];
#pragma unroll
      for (int j = 0; j < 32; ++j) acc[j] = 0.f;
#pragma unroll 2
      for (int g = 0; g < 16; ++g) {           // P = bufA quad groups 16..31
        float4 pv = *(const float4*)&bufA[(16 + g) * 256 + r * 4];
#pragma unroll
        for (int q = 0; q < 4; ++q) {
          float p = (q == 0) ? pv.x : (q == 1) ? pv.y : (q == 2) ? pv.z : pv.w;
          const int k = g * 4 + q;
          float s = fmaxf(p + qa[k], 0.f);
          const float* w2r = as_w2 + (size_t)k * 32;
#pragma unroll
          for (int j = 0; j < 32; ++j) acc[j] += s * w2r[j];
        }
      }
      float sc = b3v;
#pragma unroll
      for (int j = 0; j < 32; ++j)
        sc += fmaxf(acc[j] + as_b2[j], 0.f) * as_w3[j];
      float st = ws[1920 + a], hv = ws[1950 + a];
      float bon = (hv > 0.5f) ? (tp0 * st + tp1 * (1.f - st)) : tp3 * 2.f;
      out[(size_t)(b0 + r) * 30 + a] = sc + bon;
    }
  }
}

// ---------------------------------------------------------------------------
extern "C" void kernel_launch(void* const* d_in, const int* in_sizes, int n_in,
                              void* d_out, int out_size, void* d_ws, size_t ws_size,
                              hipStream_t stream) {
  (void)in_sizes; (void)n_in; (void)out_size; (void)ws_size;
  const int* hand_cards = (const int*)d_in[0];
  const int* enemy_card = (const int*)d_in[1];
  const int* hand_size = (const int*)d_in[2];
  const float* game_state = (const float*)d_in[3];
  const float* discard = (const float*)d_in[4];
  const int* acards = (const int*)d_in[5];
  // d_in[6] = num_valid_actions (unused scalar)
  const float* val_emb = (const float*)d_in[7];
  const float* suit_emb = (const float*)d_in[8];
  const float* type_emb = (const float*)d_in[9];
  const float* ce_w1 = (const float*)d_in[10], * ce_b1 = (const float*)d_in[11];
  const float* ce_w2 = (const float*)d_in[12], * ce_b2 = (const float*)d_in[13];
  // d_in[14..21] = ha_* (hand self-attention) -- provably dead code, unused
  const float* he_wv = (const float*)d_in[26], * he_bv = (const float*)d_in[27];
  const float* he_wo = (const float*)d_in[28], * he_bo = (const float*)d_in[29];
  const float* se_w1 = (const float*)d_in[30], * se_b1 = (const float*)d_in[31];
  const float* se_w2 = (const float*)d_in[32], * se_b2 = (const float*)d_in[33];
  const float* atc_w1 = (const float*)d_in[34], * atc_b1 = (const float*)d_in[35];
  const float* atc_w2 = (const float*)d_in[36], * atc_b2 = (const float*)d_in[37];
  const float* as_w1 = (const float*)d_in[38], * as_b1 = (const float*)d_in[39];
  const float* as_w2 = (const float*)d_in[40], * as_b2 = (const float*)d_in[41];
  const float* as_w3 = (const float*)d_in[42], * as_b3 = (const float*)d_in[43];
  const float* cx_w1 = (const float*)d_in[44], * cx_b1 = (const float*)d_in[45];
  const float* cx_w2 = (const float*)d_in[46], * cx_b2 = (const float*)d_in[47];
  const float* cx_w3 = (const float*)d_in[48], * cx_b3 = (const float*)d_in[49];
  float* ws = (float*)d_ws;
  float* out = (float*)d_out;

  hipLaunchKernelGGL(action_kernel, dim3(1), dim3(64), 0, stream,
                     acards, val_emb, suit_emb, type_emb,
                     ce_w1, ce_b1, ce_w2, ce_b2, as_w1, as_b1, ws);
  hipLaunchKernelGGL(policy_main, dim3(256), dim3(512), 0, stream,
                     hand_cards, enemy_card, hand_size, game_state, discard,
                     val_emb, suit_emb, type_emb,
                     he_wv, he_bv, he_wo, he_bo,
                     se_w1, se_b1, se_w2, se_b2,
                     atc_w1, atc_b1, atc_w2, atc_b2,
                     as_w1, as_w2, as_b2, as_w3, as_b3,
                     cx_w1, cx_b1, cx_w2, cx_b2, cx_w3, cx_b3,
                     ws, out);
}

// Round 12
// 240.131 us; speedup vs baseline: 1.1027x; 1.1027x over previous
//
#include <hip/hip_runtime.h>
#include <math.h>

// ---------------------------------------------------------------------------
// R12: single fused kernel (action precompute folded in), R8/R10 core:
// grid 256, MT=64 rows, 1024 threads (16 waves) — the occupancy ceiling for
// the lane=row design (R11 proved grid>256 is impossible at MT=64 and
// 2 blocks/CU can't exist with grid==CU count).
// Wave = 64 batch rows (lane = row); weights via wave-uniform s_load +
// SGPR-operand FMA; activations quad-packed: buf[(c>>2)*256 + r*4 + (c&3)].
// NEW: P9 runs ONE pass with TWO actions interleaved per wave — the shared
// as_w2 scalar stream + shared P reads feed two FMA chains (halves
// scalar-latency exposure on 42% of the FLOPs). Action features (wave 3,
// P0) and Qa GEMM (waves 12-15, Phase A) computed in-block into LDS.
// NO min-waves launch bound (R4: clamps VGPR -> spills).
// ---------------------------------------------------------------------------

__device__ __forceinline__ void encode_card32(int c,
                                              const float* __restrict__ val_emb,
                                              const float* __restrict__ suit_emb,
                                              const float* __restrict__ type_emb,
                                              float* e) {
  bool inv = (c == 0) || (c == 53);
  int v = inv ? 0 : ((c - 1) % 13 + 1);
  int s = inv ? 0 : ((c - 1) / 13 + 1);
  int ct = (v == 11) ? 1 : (v == 12) ? 2 : (v == 13) ? 3 : 0;
#pragma unroll
  for (int i = 0; i < 16; ++i) e[i] = val_emb[v * 16 + i];
#pragma unroll
  for (int i = 0; i < 16; ++i) e[16 + i] = suit_emb[s * 16 + i];
#pragma unroll
  for (int i = 0; i < 8; ++i) e[i] += type_emb[ct * 8 + i];
}

// ---------------------------------------------------------------------------
// Unified layer: QIN = quad-packed input (ds_read_b128, 4 k per read),
// else simple [k][64]. QOUT = quad-packed output. W read wave-uniformly.
// ---------------------------------------------------------------------------
template <int K, int NJ, bool RELU, bool HASB, bool QIN, bool QOUT>
__device__ __forceinline__ void layerU(
    const float* __restrict__ in, int inColBase, float* __restrict__ outB,
    int outColBase, const float* __restrict__ W, int ldw, int j0,
    const float* __restrict__ bias, int r) {
  float acc[NJ];
#pragma unroll
  for (int j = 0; j < NJ; ++j) acc[j] = HASB ? bias[j0 + j] : 0.f;
  if constexpr (QIN) {
    static_assert(K % 4 == 0, "quad input needs K%4==0");
    const int g0 = inColBase >> 2;
#pragma unroll 4
    for (int g = 0; g < K / 4; ++g) {
      float4 a = *(const float4*)&in[(g0 + g) * 256 + r * 4];
#pragma unroll
      for (int q = 0; q < 4; ++q) {
        float av = (q == 0) ? a.x : (q == 1) ? a.y : (q == 2) ? a.z : a.w;
        const float* wr = W + (size_t)(g * 4 + q) * ldw + j0;
#pragma unroll
        for (int j = 0; j < NJ; ++j) acc[j] += av * wr[j];
      }
    }
  } else {
#pragma unroll 4
    for (int k = 0; k < K; ++k) {
      float a = in[(inColBase + k) * 64 + r];
      const float* wr = W + (size_t)k * ldw + j0;
#pragma unroll
      for (int j = 0; j < NJ; ++j) acc[j] += a * wr[j];
    }
  }
#pragma unroll
  for (int j = 0; j < NJ; ++j) if (RELU) acc[j] = fmaxf(acc[j], 0.f);
  if constexpr (QOUT && (NJ % 4 == 0)) {
    const int c0 = outColBase + j0;      // quad-aligned by construction
#pragma unroll
    for (int qg = 0; qg < NJ / 4; ++qg) {
      float4 o = make_float4(acc[qg * 4], acc[qg * 4 + 1],
                             acc[qg * 4 + 2], acc[qg * 4 + 3]);
      *(float4*)&outB[((c0 >> 2) + qg) * 256 + r * 4] = o;
    }
  } else {
#pragma unroll
    for (int j = 0; j < NJ; ++j) outB[(outColBase + j0 + j) * 64 + r] = acc[j];
  }
}

// ---------------------------------------------------------------------------
// Fused kernel. 64 rows/block, 1024 threads (16 waves), grid 256.
// bufA (quad, 152 cols): [0:32) hand_ctx | [32:64) enemy | [64:96) strat_ctx |
//   [96:150) discard -> later h2 (128) -> later t1 [0:64) | P [64:128)
// bufB: rows [0:20) strat_in | [20:84) t64 | [84:116) V | 116 sLen
//   -> later quad h1 -> quad ctx -> logits rows [0:4)
// sScr[30*48]: act_emb [r*48+0:32) + combo [r*48+32:48)  (P0 -> Phase A)
// sQa[30*68]: Qa[a][k] at sQa[a*68+k]  (Phase A -> P9, broadcast reads)
// sMeta[64]: strength[0:30), hasv[32:62)
// ---------------------------------------------------------------------------
__global__ __launch_bounds__(1024) void policy_main(
    const int* __restrict__ hand_cards, const int* __restrict__ enemy_card,
    const int* __restrict__ hand_size, const float* __restrict__ game_state,
    const float* __restrict__ discard, const int* __restrict__ acards,
    const float* __restrict__ val_emb, const float* __restrict__ suit_emb,
    const float* __restrict__ type_emb,
    const float* __restrict__ ce_w1, const float* __restrict__ ce_b1,
    const float* __restrict__ ce_w2, const float* __restrict__ ce_b2,
    const float* __restrict__ he_wv, const float* __restrict__ he_bv,
    const float* __restrict__ he_wo, const float* __restrict__ he_bo,
    const float* __restrict__ se_w1, const float* __restrict__ se_b1,
    const float* __restrict__ se_w2, const float* __restrict__ se_b2,
    const float* __restrict__ atc_w1, const float* __restrict__ atc_b1,
    const float* __restrict__ atc_w2, const float* __restrict__ atc_b2,
    const float* __restrict__ as_w1, const float* __restrict__ as_b1,
    const float* __restrict__ as_w2, const float* __restrict__ as_b2,
    const float* __restrict__ as_w3, const float* __restrict__ as_b3,
    const float* __restrict__ cx_w1, const float* __restrict__ cx_b1,
    const float* __restrict__ cx_w2, const float* __restrict__ cx_b2,
    const float* __restrict__ cx_w3, const float* __restrict__ cx_b3,
    float* __restrict__ out) {
  __shared__ float bufA[38 * 256];   // 38 KB
  __shared__ float bufB[128 * 64];   // 32 KB
  __shared__ float sScr[30 * 48];    // 5.6 KB
  __shared__ float sQa[30 * 68];     // 8 KB (stride 68: quad-aligned, banks spread)
  __shared__ float sMeta[64];

  const int tid = threadIdx.x;
  const int r = tid & 63;                                   // lane = batch row
  const int wq = __builtin_amdgcn_readfirstlane(tid >> 6);  // wave id 0..15
  const int b0 = blockIdx.x * 64;

  // ---------------- P0: staging + per-row features + action features --------
  for (int idx = tid; idx < 64 * 54; idx += 1024) {          // discard -> bufA
    int rr = idx / 54, k = idx - rr * 54;
    int c = 96 + k;
    bufA[(c >> 2) * 256 + rr * 4 + (c & 3)] = discard[(size_t)b0 * 54 + idx];
  }
  if (wq == 2) {                                            // game_state rows 0..9
#pragma unroll
    for (int k = 0; k < 10; ++k)
      bufB[k * 64 + r] = game_state[(size_t)(b0 + r) * 10 + k];
  }
  if (wq == 0) {                                            // hand features rows 10..19
    const int b = b0 + r;
    const float hsz = (float)hand_size[b];
    int aces = 0, faces = 0, low = 0, c1 = 0, c2 = 0, c3 = 0, c4 = 0;
#pragma unroll
    for (int i = 0; i < 8; ++i) {
      int c = hand_cards[b * 8 + i];
      int v = (c == 0) ? 0 : ((c - 1) % 13 + 1);
      int s = (c == 0) ? 0 : ((c - 1) / 13 + 1);
      aces += (v == 1);
      faces += (v >= 11 && v <= 13);
      low += (v >= 2 && v <= 6);
      c1 += (s == 1); c2 += (s == 2); c3 += (s == 3); c4 += (s == 4);
    }
    float sdiv = (float)((c1 > 0) + (c2 > 0) + (c3 > 0) + (c4 > 0)) * 0.25f;
    float hvr = (float)faces / (hsz + 1e-8f);
    bufB[(10 + 0) * 64 + r] = hsz;          bufB[(10 + 1) * 64 + r] = (float)aces;
    bufB[(10 + 2) * 64 + r] = (float)faces; bufB[(10 + 3) * 64 + r] = (float)low;
    bufB[(10 + 4) * 64 + r] = (float)c1;    bufB[(10 + 5) * 64 + r] = (float)c2;
    bufB[(10 + 6) * 64 + r] = (float)c3;    bufB[(10 + 7) * 64 + r] = (float)c4;
    bufB[(10 + 8) * 64 + r] = hvr;          bufB[(10 + 9) * 64 + r] = sdiv;
  }
  if (wq == 1) {                                            // enemy (quad) + sLen
    const int b = b0 + r;
    bufB[116 * 64 + r] = 8.0f / fmaxf((float)hand_size[b], 1.0f);
    float e[32];
    encode_card32(enemy_card[b], val_emb, suit_emb, type_emb, e);
#pragma unroll
    for (int g = 0; g < 8; ++g) {
      float4 ev = make_float4(e[g * 4], e[g * 4 + 1], e[g * 4 + 2], e[g * 4 + 3]);
      *(float4*)&bufA[(8 + g) * 256 + r * 4] = ev;   // cols 32..63
    }
  }
  if (wq == 3 && r < 30) {                                  // action features
    int c[4];
#pragma unroll
    for (int i = 0; i < 4; ++i) c[i] = acards[r * 4 + i];
    bool mask[4]; int vals[4], suits[4]; int csize = 0; bool hasv = false;
#pragma unroll
    for (int i = 0; i < 4; ++i) {
      mask[i] = (c[i] != 0);
      if (mask[i]) { csize++; hasv = true; }
      vals[i] = mask[i] ? ((c[i] - 1) % 13 + 1) : 0;
      suits[i] = mask[i] ? ((c[i] - 1) / 13 + 1) : 0;
    }
    int fvv = mask[0] ? vals[0] : mask[1] ? vals[1] : mask[2] ? vals[2]
              : mask[3] ? vals[3] : vals[0];
    bool same = true;
#pragma unroll
    for (int i = 0; i < 4; ++i) if (mask[i] && vals[i] != fvv) same = false;
    float total = 0.f;
#pragma unroll
    for (int i = 0; i < 4; ++i) {
      if (mask[i]) {
        int v = vals[i];
        total += (v == 1) ? 1.f : (v == 11) ? 10.f : (v == 12) ? 15.f
                 : (v == 13) ? 20.f : (float)v;
      }
    }
    float uniq = 0.f;
#pragma unroll
    for (int s = 1; s <= 4; ++s) {
      bool any = false;
#pragma unroll
      for (int i = 0; i < 4; ++i) if (suits[i] == s) any = true;
      uniq += any ? 1.f : 0.f;
    }
    bool ace = false;
#pragma unroll
    for (int i = 0; i < 4; ++i) if (mask[i] && vals[i] == 1) ace = true;
    float f_same = same ? 1.f : 0.f, f_ace = ace ? 1.f : 0.f;
    float valid = (((float)csize <= 4.f) && (f_same > 0.f || f_ace > 0.f)) ? 1.f : 0.f;
    float feats[6] = {(float)csize, f_same, total, uniq, f_ace, valid};
    if (!hasv) { for (int i = 0; i < 6; ++i) feats[i] = 0.f; }
    float emb[32];
#pragma unroll
    for (int i = 0; i < 32; ++i) emb[i] = 0.f;
    float cnt = 0.f;
#pragma unroll
    for (int i = 0; i < 4; ++i) {
      float e[32];
      encode_card32(c[i], val_emb, suit_emb, type_emb, e);
      if (mask[i]) {
#pragma unroll
        for (int j = 0; j < 32; ++j) emb[j] += e[j];
        cnt += 1.f;
      }
    }
    float invc = 1.f / fmaxf(cnt, 1.f);
#pragma unroll
    for (int j = 0; j < 32; ++j)
      sScr[r * 48 + j] = hasv ? emb[j] * invc : 0.f;
    float t32[32];
#pragma unroll
    for (int j = 0; j < 32; ++j) {
      float acc = ce_b1[j];
#pragma unroll
      for (int k = 0; k < 6; ++k) acc += feats[k] * ce_w1[k * 32 + j];
      t32[j] = fmaxf(acc, 0.f);
    }
#pragma unroll
    for (int j = 0; j < 16; ++j) {
      float acc = ce_b2[j];
#pragma unroll
      for (int k = 0; k < 32; ++k) acc += t32[k] * ce_w2[k * 16 + j];
      sScr[r * 48 + 32 + j] = acc;
    }
    sMeta[r] = total * 0.05f;
    sMeta[32 + r] = hasv ? 1.f : 0.f;
  }
  __syncthreads();

  // ---------------- Phase A: se L1 (0-7) | V (8-11) | Qa (12-15) ------------
  if (wq < 8) {
    layerU<20, 8, true, true, false, false>(bufB, 0, bufB, 20, se_w1, 64,
                                            wq * 8, se_b1, r);
  } else if (wq < 12) {
    layerU<32, 8, false, true, true, false>(bufA, 32, bufB, 84, he_wv, 32,
                                            (wq - 8) * 8, he_bv, r);
  } else if (r < 30) {
    // Qa[a=r][j0:j0+16) = act_emb@as_w1[128:160] + combo@as_w1[160:176] + as_b1
    const int j0 = (wq - 12) * 16;
    float acc[16];
#pragma unroll
    for (int j = 0; j < 16; ++j) acc[j] = as_b1[j0 + j];
#pragma unroll 4
    for (int k = 0; k < 32; ++k) {
      float a = sScr[r * 48 + k];
      const float* wr = as_w1 + (size_t)(128 + k) * 64 + j0;
#pragma unroll
      for (int j = 0; j < 16; ++j) acc[j] += a * wr[j];
    }
#pragma unroll
    for (int k = 0; k < 16; ++k) {
      float a = sScr[r * 48 + 32 + k];
      const float* wr = as_w1 + (size_t)(160 + k) * 64 + j0;
#pragma unroll
      for (int j = 0; j < 16; ++j) acc[j] += a * wr[j];
    }
#pragma unroll
    for (int j = 0; j < 16; ++j) sQa[r * 68 + j0 + j] = acc[j];
  }
  __syncthreads();

  // ---------------- Phase B: se L2 (0-7) | hand_ctx (8-15) ------------------
  if (wq < 8) {
    layerU<64, 4, false, true, false, true>(bufB, 20, bufA, 64, se_w2, 32,
                                            wq * 4, se_b2, r);
  } else {
    const int j0 = (wq - 8) * 4;
    float acc[4];
#pragma unroll
    for (int j = 0; j < 4; ++j) acc[j] = he_bo[j0 + j];
#pragma unroll 4
    for (int k = 0; k < 32; ++k) {
      float a = bufB[(84 + k) * 64 + r];
      const float* wr = he_wo + (size_t)k * 32 + j0;
#pragma unroll
      for (int j = 0; j < 4; ++j) acc[j] += a * wr[j];
    }
    float scale = bufB[116 * 64 + r];
    float4 o = make_float4(scale * acc[0], scale * acc[1],
                           scale * acc[2], scale * acc[3]);
    *(float4*)&bufA[(j0 >> 2) * 256 + r * 4] = o;
  }
  __syncthreads();

  // ---------------- L1: 150->128 relu, all input in LDS ---------------------
  {
    const int j0 = wq * 8;
    float acc[8];
#pragma unroll
    for (int j = 0; j < 8; ++j) acc[j] = cx_b1[j0 + j];
#pragma unroll 4
    for (int g = 0; g < 37; ++g) {
      float4 a = *(const float4*)&bufA[g * 256 + r * 4];
#pragma unroll
      for (int q = 0; q < 4; ++q) {
        float av = (q == 0) ? a.x : (q == 1) ? a.y : (q == 2) ? a.z : a.w;
        const float* wr = cx_w1 + (size_t)(g * 4 + q) * 128 + j0;
#pragma unroll
        for (int j = 0; j < 8; ++j) acc[j] += av * wr[j];
      }
    }
    {  // tail: cols 148,149
      float4 a = *(const float4*)&bufA[37 * 256 + r * 4];
      const float* wr0 = cx_w1 + (size_t)148 * 128 + j0;
      const float* wr1 = cx_w1 + (size_t)149 * 128 + j0;
#pragma unroll
      for (int j = 0; j < 8; ++j) acc[j] += a.x * wr0[j] + a.y * wr1[j];
    }
#pragma unroll
    for (int qg = 0; qg < 2; ++qg) {
      float4 o = make_float4(fmaxf(acc[qg * 4], 0.f), fmaxf(acc[qg * 4 + 1], 0.f),
                             fmaxf(acc[qg * 4 + 2], 0.f), fmaxf(acc[qg * 4 + 3], 0.f));
      *(float4*)&bufB[((j0 >> 2) + qg) * 256 + r * 4] = o;
    }
  }
  __syncthreads();

  // ---------------- L2 / L3 / P7 --------------------------------------------
  layerU<128, 8, true, true, true, true>(bufB, 0, bufA, 0, cx_w2, 128, wq * 8,
                                         cx_b2, r);
  __syncthreads();
  layerU<128, 8, false, true, true, true>(bufA, 0, bufB, 0, cx_w3, 128, wq * 8,
                                          cx_b3, r);
  __syncthreads();
  if (wq < 8) {
    layerU<128, 8, true, true, true, true>(bufB, 0, bufA, 0, atc_w1, 64,
                                           wq * 8, atc_b1, r);
  } else {
    layerU<128, 8, false, false, true, true>(bufB, 0, bufA, 64, as_w1, 64,
                                             (wq - 8) * 8, nullptr, r);
  }
  __syncthreads();

  // ---------------- P8: 4 type logits ---------------------------------------
  if (wq < 4) {
    float acc = atc_b2[wq];
#pragma unroll 4
    for (int g = 0; g < 16; ++g) {
      float4 t = *(const float4*)&bufA[g * 256 + r * 4];
      acc += t.x * atc_w2[(g * 4 + 0) * 4 + wq];
      acc += t.y * atc_w2[(g * 4 + 1) * 4 + wq];
      acc += t.z * atc_w2[(g * 4 + 2) * 4 + wq];
      acc += t.w * atc_w2[(g * 4 + 3) * 4 + wq];
    }
    bufB[wq * 64 + r] = acc;
  }
  __syncthreads();

  // ---------------- P9: waves 0-14, TWO actions interleaved per wave --------
  if (wq < 15) {
    float l0 = bufB[0 * 64 + r], l1 = bufB[1 * 64 + r];
    float l2 = bufB[2 * 64 + r], l3 = bufB[3 * 64 + r];
    float m = fmaxf(fmaxf(l0, l1), fmaxf(l2, l3));
    float e0 = expf(l0 - m), e1 = expf(l1 - m), e2 = expf(l2 - m), e3 = expf(l3 - m);
    float inv = 1.f / (e0 + e1 + e2 + e3);
    float tp0 = e0 * inv, tp1 = e1 * inv, tp3 = e3 * inv;

    const int a0 = wq * 2, a1 = a0 + 1;
    float acc0[32], acc1[32];
#pragma unroll
    for (int j = 0; j < 32; ++j) { acc0[j] = 0.f; acc1[j] = 0.f; }
#pragma unroll 2
    for (int g = 0; g < 16; ++g) {           // P = bufA quad groups 16..31
      float4 pv = *(const float4*)&bufA[(16 + g) * 256 + r * 4];
      float4 q0 = *(const float4*)&sQa[a0 * 68 + g * 4];   // broadcast
      float4 q1 = *(const float4*)&sQa[a1 * 68 + g * 4];   // broadcast
#pragma unroll
      for (int q = 0; q < 4; ++q) {
        float p  = (q == 0) ? pv.x : (q == 1) ? pv.y : (q == 2) ? pv.z : pv.w;
        float qa0v = (q == 0) ? q0.x : (q == 1) ? q0.y : (q == 2) ? q0.z : q0.w;
        float qa1v = (q == 0) ? q1.x : (q == 1) ? q1.y : (q == 2) ? q1.z : q1.w;
        float s0 = fmaxf(p + qa0v, 0.f);
        float s1 = fmaxf(p + qa1v, 0.f);
        const float* w2r = as_w2 + (size_t)(g * 4 + q) * 32;   // shared stream
#pragma unroll
        for (int j = 0; j < 32; ++j) {
          float w = w2r[j];
          acc0[j] += s0 * w;
          acc1[j] += s1 * w;
        }
      }
    }
    const float b3v = as_b3[0];
    float sc0 = b3v, sc1 = b3v;
#pragma unroll
    for (int j = 0; j < 32; ++j) {
      float bb2 = as_b2[j], w3 = as_w3[j];
      sc0 += fmaxf(acc0[j] + bb2, 0.f) * w3;
      sc1 += fmaxf(acc1[j] + bb2, 0.f) * w3;
    }
    float st0 = sMeta[a0], hv0 = sMeta[32 + a0];
    float st1 = sMeta[a1], hv1 = sMeta[32 + a1];
    float bon0 = (hv0 > 0.5f) ? (tp0 * st0 + tp1 * (1.f - st0)) : tp3 * 2.f;
    float bon1 = (hv1 > 0.5f) ? (tp0 * st1 + tp1 * (1.f - st1)) : tp3 * 2.f;
    out[(size_t)(b0 + r) * 30 + a0] = sc0 + bon0;
    out[(size_t)(b0 + r) * 30 + a1] = sc1 + bon1;
  }
}

// ---------------------------------------------------------------------------
extern "C" void kernel_launch(void* const* d_in, const int* in_sizes, int n_in,
                              void* d_out, int out_size, void* d_ws, size_t ws_size,
                              hipStream_t stream) {
  (void)in_sizes; (void)n_in; (void)out_size; (void)d_ws; (void)ws_size;
  const int* hand_cards = (const int*)d_in[0];
  const int* enemy_card = (const int*)d_in[1];
  const int* hand_size = (const int*)d_in[2];
  const float* game_state = (const float*)d_in[3];
  const float* discard = (const float*)d_in[4];
  const int* acards = (const int*)d_in[5];
  // d_in[6] = num_valid_actions (unused scalar)
  const float* val_emb = (const float*)d_in[7];
  const float* suit_emb = (const float*)d_in[8];
  const float* type_emb = (const float*)d_in[9];
  const float* ce_w1 = (const float*)d_in[10], * ce_b1 = (const float*)d_in[11];
  const float* ce_w2 = (const float*)d_in[12], * ce_b2 = (const float*)d_in[13];
  // d_in[14..21] = ha_* (hand self-attention) -- provably dead code, unused
  const float* he_wv = (const float*)d_in[26], * he_bv = (const float*)d_in[27];
  const float* he_wo = (const float*)d_in[28], * he_bo = (const float*)d_in[29];
  const float* se_w1 = (const float*)d_in[30], * se_b1 = (const float*)d_in[31];
  const float* se_w2 = (const float*)d_in[32], * se_b2 = (const float*)d_in[33];
  const float* atc_w1 = (const float*)d_in[34], * atc_b1 = (const float*)d_in[35];
  const float* atc_w2 = (const float*)d_in[36], * atc_b2 = (const float*)d_in[37];
  const float* as_w1 = (const float*)d_in[38], * as_b1 = (const float*)d_in[39];
  const float* as_w2 = (const float*)d_in[40], * as_b2 = (const float*)d_in[41];
  const float* as_w3 = (const float*)d_in[42], * as_b3 = (const float*)d_in[43];
  const float* cx_w1 = (const float*)d_in[44], * cx_b1 = (const float*)d_in[45];
  const float* cx_w2 = (const float*)d_in[46], * cx_b2 = (const float*)d_in[47];
  const float* cx_w3 = (const float*)d_in[48], * cx_b3 = (const float*)d_in[49];
  float* out = (float*)d_out;

  hipLaunchKernelGGL(policy_main, dim3(256), dim3(1024), 0, stream,
                     hand_cards, enemy_card, hand_size, game_state, discard,
                     acards, val_emb, suit_emb, type_emb,
                     ce_w1, ce_b1, ce_w2, ce_b2,
                     he_wv, he_bv, he_wo, he_bo,
                     se_w1, se_b1, se_w2, se_b2,
                     atc_w1, atc_b1, atc_w2, atc_b2,
                     as_w1, as_b1, as_w2, as_b2, as_w3, as_b3,
                     cx_w1, cx_b1, cx_w2, cx_b2, cx_w3, cx_b3,
                     out);
}